// Round 5
// baseline (251.108 us; speedup 1.0000x reference)
//
#include <hip/hip_runtime.h>

#define BB 4
#define NN 16384
#define SS 4096
#define CC 256
#define TLD 261  // gather tile leading dim (odd -> store-phase rows spread all 32 banks)

typedef float f32x4 __attribute__((ext_vector_type(4)));  // for nontemporal builtins

__device__ __forceinline__ bool lexlt(float da, int ia, float db, int ib) {
  // strict (d, idx) lexicographic order — matches jax.lax.top_k tie-break
  return (da < db) || ((da == db) && (ia < ib));
}

// ---------------- Kernel P: pack candidates as {x,y,z,kk} ----------------
// kk = (x*x + y*y) + z*z, np left-to-right order, contract off — byte-identical
// to the staging math previously done in-kernel. 256 KB workspace.
__global__ __launch_bounds__(256) void prep_kernel(const float* __restrict__ kg,
                                                   float4* __restrict__ cand) {
#pragma clang fp contract(off)
  int gid = blockIdx.x * 256 + threadIdx.x;  // 16384 = BB*SS
  int b = gid >> 12, s = gid & 4095;
  const float* kp = kg + ((long)b * SS + s) * 3;
  float x = kp[0], y = kp[1], z = kp[2];
  float kk = (x * x + y * y) + z * z;
  cand[(long)b * SS + s] = make_float4(x, y, z, kk);
}

// ---------------- Fused kernel: long-window skip-gated scan + gather ----------------
// Grid 1024 x 128 thr (2 waves). Block owns 64 queries (lane = query).
// Wave w scans contiguous candidate window [w*2048, (w+1)*2048) for ALL 64 queries:
// candidate is wave-uniform (LDS broadcast read), each lane keeps its own top-3.
// KEY: with a 2048-long window and only 64 query slots, P(any lane inserts at
// local step t) ~ 1-(1-3/t)^64 -> the 11-op insert executes only ~32% of steps;
// `if (__any(d < d2))` skips it wave-uniformly. Insert body & all FP math are
// byte-identical to prior rounds (exact np replication, contract off).
// Then: 2-way in-LDS merge (no partials round-trip), weights, fused gather+
// transpose+NT store. XCD affinity: b=(bid>>1)&3 -> each XCD pair serves one
// batch's V (4 MB ~ L2). 4 blocks/CU exactly (grid 1024), 8 waves/CU.
__global__ __launch_bounds__(128, 2) void fused_kernel(
    const float* __restrict__ qg, const float4* __restrict__ cand,
    const float* __restrict__ vg, float* __restrict__ outg) {
#pragma clang fp contract(off)
  // phase-disjoint union: [scan: kst 2x512 f4 =16KB][merge: wm/im 3KB][gather: tile 33.4KB]
  __shared__ __align__(16) char buf[32 * TLD * 4];
  __shared__ float sw[64][3];
  __shared__ int si[64][3];
  float4* kst = (float4*)buf;      // [2][512] staged candidates (per-wave halves)
  float* tile = (float*)buf;       // [32][TLD] gather/transpose tile
  float* wm = (float*)buf;         // [2][64][3] merge floats
  int* im = (int*)(buf + 1536);    // [2][64][3] merge ints

  const int tid = threadIdx.x;
  const int bid = blockIdx.x;
  const int b = (bid >> 1) & 3;    // round-robin: XCDs {2b, 2b+1} own batch b
  const int n0 = (((bid & 1) << 7) + (bid >> 3)) << 6;  // 64 queries per block
  const int w = tid >> 6;          // wave 0/1 -> candidate window halves
  const int lane = tid & 63;       // lane = query

  // ---- per-lane query ----
  const float* qp = qg + ((long)b * NN + n0 + lane) * 3;
  float qx = qp[0], qy = qp[1], qz = qp[2];
  float qq = (qx * qx + qy * qy) + qz * qz;  // np sum order
  float d0 = 3.4e38f, d1 = 3.4e38f, d2 = 3.4e38f;
  int i0 = 0, i1 = 0, i2 = 0;

  // ---- scan: 4 chunks of 512 candidates, per-wave LDS staging ----
  const float4* csrc = cand + (long)b * SS + w * 2048;
  for (int c = 0; c < 4; ++c) {
    float4 tmp[8];
#pragma unroll
    for (int m = 0; m < 8; ++m) tmp[m] = csrc[c * 512 + lane + 64 * m];
    __syncthreads();  // prior chunk's broadcast reads complete before overwrite
#pragma unroll
    for (int m = 0; m < 8; ++m) kst[w * 512 + lane + 64 * m] = tmp[m];
    __syncthreads();
    const int sbase = w * 2048 + c * 512;
#pragma unroll 4
    for (int i = 0; i < 512; ++i) {
      float4 kp = kst[w * 512 + i];  // wave-uniform broadcast, conflict-free
      // exact np replication: d = qq - 2*dot + kk, left-to-right, no contract.
      float dot = (qx * kp.x + qy * kp.y) + qz * kp.z;
      float d = __builtin_fmaf(dot, -2.0f, qq) + kp.w;
      // skip the insert when NO lane would update (identical predicate to k2)
      if (__builtin_expect(__any(d < d2), 0)) {
        const int s = sbase + i;
        bool k2 = d < d2;
        bool k1 = d < d1;
        bool k0 = d < d0;
        // sorted invariant d0<=d1<=d2 makes med3 the exact shifted value
        float nd2 = __builtin_amdgcn_fmed3f(d, d1, d2);
        float nd1 = __builtin_amdgcn_fmed3f(d, d0, d1);
        float nd0 = fminf(d, d0);
        i2 = k1 ? i1 : (k2 ? s : i2);
        i1 = k0 ? i0 : (k1 ? s : i1);
        i0 = k0 ? s : i0;
        d2 = nd2; d1 = nd1; d0 = nd0;
      }
    }
  }

  // ---- 2-way merge via LDS (wm/im overlay dead staging region) ----
  __syncthreads();  // all kst reads done
  {
    int base = (w * 64 + lane) * 3;
    wm[base + 0] = d0; wm[base + 1] = d1; wm[base + 2] = d2;
    im[base + 0] = i0; im[base + 1] = i1; im[base + 2] = i2;
  }
  __syncthreads();

  if (tid < 64) {
    float D0 = 3.4e38f, D1 = 3.4e38f, D2 = 3.4e38f;
    int I0 = -1, I1 = -1, I2 = -1;
    for (int wv = 0; wv < 2; ++wv) {
      int base = (wv * 64 + tid) * 3;
      for (int r = 0; r < 3; ++r) {
        float d = wm[base + r];
        int s = im[base + r];
        if (lexlt(d, s, D2, I2)) {
          if (lexlt(d, s, D1, I1)) {
            D2 = D1; I2 = I1;
            if (lexlt(d, s, D0, I0)) { D1 = D0; I1 = I0; D0 = d; I0 = s; }
            else { D1 = d; I1 = s; }
          } else { D2 = d; I2 = s; }
        }
      }
    }
    // weights exactly as ref: recip = 1/(d+1e-8) on ascending dists, then normalize
    float r0 = 1.0f / (D0 + 1e-8f);
    float r1 = 1.0f / (D1 + 1e-8f);
    float r2 = 1.0f / (D2 + 1e-8f);
    float rs = (r0 + r1) + r2;
    sw[tid][0] = r0 / rs; sw[tid][1] = r1 / rs; sw[tid][2] = r2 / rs;
    si[tid][0] = I0; si[tid][1] = I1; si[tid][2] = I2;
  }
  __syncthreads();  // fences wm/im reads before tile overlays them

  // ---- gather + weighted sum + transpose, 2 chunks of 32 queries ----
  const float* vb = vg + (long)b * SS * CC;
#pragma unroll
  for (int chunk = 0; chunk < 2; ++chunk) {
    // fill: each wave fills 16 rows; 64 lanes = 64 f4 slots = full 256-ch row
#pragma unroll 2
    for (int it = 0; it < 16; ++it) {
      int qs = chunk * 32 + w * 16 + it;
      float w0 = sw[qs][0], w1 = sw[qs][1], w2 = sw[qs][2];
      const float4* r0p = (const float4*)(vb + (long)si[qs][0] * CC);
      const float4* r1p = (const float4*)(vb + (long)si[qs][1] * CC);
      const float4* r2p = (const float4*)(vb + (long)si[qs][2] * CC);
      float4 a0 = r0p[lane], a1 = r1p[lane], a2 = r2p[lane];
      float4 acc;
      acc.x = (w0 * a0.x + w1 * a1.x) + w2 * a2.x;
      acc.y = (w0 * a0.y + w1 * a1.y) + w2 * a2.y;
      acc.z = (w0 * a0.z + w1 * a1.z) + w2 * a2.z;
      acc.w = (w0 * a0.w + w1 * a1.w) + w2 * a2.w;
      *(float4*)&tile[(w * 16 + it) * TLD + lane * 4] = acc;
    }
    __syncthreads();
    // store: 256 ch x 32 n; thread assembles float4 along n; NT dwordx4
#pragma unroll 2
    for (int it = 0; it < 16; ++it) {
      int item = it * 128 + tid;
      int nf = item & 7;        // f4 group along n (0..7)
      int cch = item >> 3;      // channel 0..255
      f32x4 val;
      val.x = tile[(nf * 4 + 0) * TLD + cch];
      val.y = tile[(nf * 4 + 1) * TLD + cch];
      val.z = tile[(nf * 4 + 2) * TLD + cch];
      val.w = tile[(nf * 4 + 3) * TLD + cch];
      __builtin_nontemporal_store(
          val, (f32x4*)&outg[((long)(b * CC + cch)) * NN + n0 + chunk * 32 + nf * 4]);
    }
    __syncthreads();  // tile reused by next chunk
  }
}

extern "C" void kernel_launch(void* const* d_in, const int* in_sizes, int n_in,
                              void* d_out, int out_size, void* d_ws, size_t ws_size,
                              hipStream_t stream) {
  const float* q = (const float*)d_in[0];
  const float* k = (const float*)d_in[1];
  const float* v = (const float*)d_in[2];
  float* out = (float*)d_out;
  float4* cand = (float4*)d_ws;  // 256 KB packed candidates
  hipLaunchKernelGGL(prep_kernel, dim3(64), dim3(256), 0, stream, k, cand);
  hipLaunchKernelGGL(fused_kernel, dim3(1024), dim3(128), 0, stream, q, cand, v, out);
}

// Round 6
// 219.678 us; speedup vs baseline: 1.1431x; 1.1431x over previous
//
#include <hip/hip_runtime.h>

#define BB 4
#define NN 16384
#define SS 4096
#define CC 256
#define TLD 132  // gather tile leading dim (words): 128ch + 4 pad, rows 16B-aligned

typedef float f32x4 __attribute__((ext_vector_type(4)));  // for nontemporal builtins

__device__ __forceinline__ bool lexlt(float da, int ia, float db, int ib) {
  // strict (d, idx) lexicographic order — matches jax.lax.top_k tie-break
  return (da < db) || ((da == db) && (ia < ib));
}

// ---------------- Kernel A: gated partial top-3 scan, lane = query ----------------
// Grid 1024 = b(4) x seg(4) x nq(64); 256 thr (4 waves); 4 blocks/CU, 16 waves/CU.
// Each wave owns 64 queries (one per lane) over the segment's full 1024 candidates.
// Candidates staged once in 16 KB LDS, read as wave-uniform broadcasts (0 conflicts).
// First 256 candidates: ungated insert (seeds top-3). Remaining 768: wave-level gate
// `__any(d < tau)` with tau = d2 FROZEN per 256-chunk -> loop-invariant gate, fully
// pipelineable distances, ~35% open fraction => ~24% fewer executed VALU ops.
// Exact: insert executes iff d < d2_running <= tau, body byte-identical, s ascending.
__global__ __launch_bounds__(256, 4) void scan_kernel(
    const float* __restrict__ qg, const float* __restrict__ kg,
    float4* __restrict__ dpart, int4* __restrict__ ipart) {
#pragma clang fp contract(off)
  __shared__ __align__(16) float4 kpts[1024];  // 16 KB

  const int tid = threadIdx.x;
  const int blk = blockIdx.x;
  const int b = blk >> 8;
  const int seg = (blk >> 6) & 3;
  const int n0 = (blk & 63) << 8;  // 256 queries per block
  const int wv = tid >> 6;
  const int lane = tid & 63;
  const int q = n0 + wv * 64 + lane;  // this lane's query

  // ---- stage this segment's 1024 points as {x,y,z,kk} ----
  {
    const float* kb = kg + ((long)b * SS + (long)seg * 1024) * 3;
    const float4* src = (const float4*)kb + tid * 3;
    float4 f0 = src[0], f1 = src[1], f2 = src[2];
    float px[4] = {f0.x, f0.w, f1.z, f2.y};
    float py[4] = {f0.y, f1.x, f1.w, f2.z};
    float pz[4] = {f0.z, f1.y, f2.x, f2.w};
#pragma unroll
    for (int m = 0; m < 4; ++m) {
      float kk = (px[m] * px[m] + py[m] * py[m]) + pz[m] * pz[m];  // np order
      kpts[tid * 4 + m] = make_float4(px[m], py[m], pz[m], kk);
    }
  }

  const float* qp = qg + ((long)b * NN + q) * 3;
  float qx = qp[0], qy = qp[1], qz = qp[2];
  float qq = (qx * qx + qy * qy) + qz * qz;  // np sum order
  float d0 = 3.4e38f, d1 = 3.4e38f, d2 = 3.4e38f;
  int i0 = 0, i1 = 0, i2 = 0;
  __syncthreads();

  const int sb = seg * 1024;

  // ---- prefix 256: ungated full insert (seeds the top-3) ----
#pragma unroll 4
  for (int i = 0; i < 256; ++i) {
    float4 kp = kpts[i];  // wave-uniform broadcast
    // exact np replication: d = qq - 2*dot + kk, left-to-right, no contract.
    float dot = (qx * kp.x + qy * kp.y) + qz * kp.z;
    float d = __builtin_fmaf(dot, -2.0f, qq) + kp.w;
    const int s = sb + i;
    bool k2 = d < d2;
    bool k1 = d < d1;
    bool k0 = d < d0;
    // sorted invariant d0<=d1<=d2 makes med3 the exact shifted value
    float nd2 = __builtin_amdgcn_fmed3f(d, d1, d2);
    float nd1 = __builtin_amdgcn_fmed3f(d, d0, d1);
    float nd0 = fminf(d, d0);
    i2 = k1 ? i1 : (k2 ? s : i2);
    i1 = k0 ? i0 : (k1 ? s : i1);
    i0 = k0 ? s : i0;
    d2 = nd2; d1 = nd1; d0 = nd0;
  }

  // ---- gated chunks: tau frozen per 256 candidates (loop-invariant gate) ----
  for (int c = 1; c < 4; ++c) {
    const float tau = d2;  // per-lane; d2_running <= tau within the chunk
    const int base = c * 256;
#pragma unroll 4
    for (int i = 0; i < 256; ++i) {
      float4 kp = kpts[base + i];
      float dot = (qx * kp.x + qy * kp.y) + qz * kp.z;
      float d = __builtin_fmaf(dot, -2.0f, qq) + kp.w;
      // any needed insert satisfies d < d2_running <= tau -> never missed
      if (__builtin_expect(__any(d < tau), 0)) {
        const int s = sb + base + i;
        bool k2 = d < d2;
        bool k1 = d < d1;
        bool k0 = d < d0;
        float nd2 = __builtin_amdgcn_fmed3f(d, d1, d2);
        float nd1 = __builtin_amdgcn_fmed3f(d, d0, d1);
        float nd0 = fminf(d, d0);
        i2 = k1 ? i1 : (k2 ? s : i2);
        i1 = k0 ? i0 : (k1 ? s : i1);
        i0 = k0 ? s : i0;
        d2 = nd2; d1 = nd1; d0 = nd0;
      }
    }
  }

  // ---- write this lane's partial (no intra-block merge needed) ----
  long gid = (long)b * NN + q;
  dpart[gid * 4 + seg] = make_float4(d0, d1, d2, 0.0f);
  ipart[gid * 4 + seg] = make_int4(i0, i1, i2, 0);
}

// ---------------- Kernel B: merge partials + gather + transpose ----------------
// Verbatim R3 (v3b): XCD-affinity decomposition, measured ~21 us. Grid 2048;
// round-robin dispatch -> XCD = bid&7; each XCD owns one (batch, channel-half):
// per-XCD V working set 2 MB < 4 MB L2. NT stores keep writes from evicting V.
__global__ __launch_bounds__(256, 4) void gather_kernel(
    const float* __restrict__ vg, const float4* __restrict__ dpart,
    const int4* __restrict__ ipart, float* __restrict__ outg) {
#pragma clang fp contract(off)
  __shared__ __align__(16) float tile[64 * TLD];  // 33.8 KB
  __shared__ float sw[64][3];
  __shared__ int si[64][3];

  const int tid = threadIdx.x;
  const int bid = blockIdx.x;
  const int xcd = bid & 7;     // dispatch round-robin: block -> XCD
  const int b = xcd >> 1;      // 2 XCDs per batch
  const int chunk = xcd & 1;   // which 128-channel half this XCD handles
  const int nblk = bid >> 3;   // 0..255
  const int n0 = nblk << 6;    // 64 queries per block

  if (tid < 64) {
    long gid = (long)b * NN + n0 + tid;
    float D0 = 3.4e38f, D1 = 3.4e38f, D2 = 3.4e38f;
    int I0 = -1, I1 = -1, I2 = -1;
#pragma unroll
    for (int seg = 0; seg < 4; ++seg) {
      float4 dv = dpart[gid * 4 + seg];
      int4 iv = ipart[gid * 4 + seg];
      float ds_[3] = {dv.x, dv.y, dv.z};
      int is_[3] = {iv.x, iv.y, iv.z};
      for (int r = 0; r < 3; ++r) {
        float d = ds_[r];
        int s = is_[r];
        if (lexlt(d, s, D2, I2)) {
          if (lexlt(d, s, D1, I1)) {
            D2 = D1; I2 = I1;
            if (lexlt(d, s, D0, I0)) { D1 = D0; I1 = I0; D0 = d; I0 = s; }
            else { D1 = d; I1 = s; }
          } else { D2 = d; I2 = s; }
        }
      }
    }
    // weights exactly as ref: recip = 1/(d+1e-8) on ascending dists, then normalize
    float r0 = 1.0f / (D0 + 1e-8f);
    float r1 = 1.0f / (D1 + 1e-8f);
    float r2 = 1.0f / (D2 + 1e-8f);
    float rs = (r0 + r1) + r2;
    sw[tid][0] = r0 / rs; sw[tid][1] = r1 / rs; sw[tid][2] = r2 / rs;
    si[tid][0] = I0; si[tid][1] = I1; si[tid][2] = I2;
  }
  __syncthreads();

  const int wv = tid >> 6;      // wave id 0..3 -> owns queries wv*16 .. wv*16+15
  const int lane = tid & 63;
  const int qh = lane >> 5;     // half-wave: which of 2 queries this iteration
  const int slot = lane & 31;   // f4 slot within the 128-channel half
  const float* vb = vg + (long)b * SS * CC + chunk * 128;

#pragma unroll 4
  for (int it = 0; it < 8; ++it) {
    int qs = wv * 16 + it * 2 + qh;
    float w0 = sw[qs][0], w1 = sw[qs][1], w2 = sw[qs][2];
    const float4* r0p = (const float4*)(vb + (long)si[qs][0] * CC);
    const float4* r1p = (const float4*)(vb + (long)si[qs][1] * CC);
    const float4* r2p = (const float4*)(vb + (long)si[qs][2] * CC);
    float4 a0 = r0p[slot], a1 = r1p[slot], a2 = r2p[slot];
    float4 acc;
    acc.x = (w0 * a0.x + w1 * a1.x) + w2 * a2.x;
    acc.y = (w0 * a0.y + w1 * a1.y) + w2 * a2.y;
    acc.z = (w0 * a0.z + w1 * a1.z) + w2 * a2.z;
    acc.w = (w0 * a0.w + w1 * a1.w) + w2 * a2.w;
    *(float4*)&tile[qs * TLD + slot * 4] = acc;
  }
  __syncthreads();

  // store: 128 channels x 64 n; each thread assembles float4 along n (non-temporal)
  {
    const int nf = tid & 15;   // f4 group along n
    const int cb0 = tid >> 4;  // channel base 0..15
    const int q0 = nf << 2;    // first of 4 consecutive queries (n)
#pragma unroll 2
    for (int it = 0; it < 8; ++it) {
      int cl = cb0 + it * 16;           // channel within half 0..127
      int cch = (chunk << 7) + cl;      // global channel
      f32x4 val;
      val.x = tile[(q0 + 0) * TLD + cl];
      val.y = tile[(q0 + 1) * TLD + cl];
      val.z = tile[(q0 + 2) * TLD + cl];
      val.w = tile[(q0 + 3) * TLD + cl];
      __builtin_nontemporal_store(
          val, (f32x4*)&outg[((long)(b * CC + cch)) * NN + n0 + q0]);
    }
  }
}

extern "C" void kernel_launch(void* const* d_in, const int* in_sizes, int n_in,
                              void* d_out, int out_size, void* d_ws, size_t ws_size,
                              hipStream_t stream) {
  const float* q = (const float*)d_in[0];
  const float* k = (const float*)d_in[1];
  const float* v = (const float*)d_in[2];
  float* out = (float*)d_out;
  float4* dpart = (float4*)d_ws;                                          // 4 MB
  int4* ipart = (int4*)((char*)d_ws + (size_t)BB * NN * 4 * 16);          // 4 MB
  hipLaunchKernelGGL(scan_kernel, dim3(1024), dim3(256), 0, stream, q, k, dpart, ipart);
  hipLaunchKernelGGL(gather_kernel, dim3(2048), dim3(256), 0, stream, v, dpart, ipart, out);
}